// Round 1
// baseline (119.728 us; speedup 1.0000x reference)
//
#include <hip/hip_runtime.h>

typedef __bf16 bf16;
typedef __bf16 bf16x4 __attribute__((ext_vector_type(4)));
typedef __bf16 bf16x8 __attribute__((ext_vector_type(8)));
typedef float  f32x16 __attribute__((ext_vector_type(16)));

#define CIN    256
#define KK     9
#define KDIM   2304
#define KSTEPS 144           // KDIM / 16  (K-steps of the 32x32x16 MFMA)
#define PXW    32            // pixels per WG

// force a wave-uniform value into an SGPR
__device__ __forceinline__ float sread(float f) {
    return __builtin_bit_cast(float,
        __builtin_amdgcn_readfirstlane(__builtin_bit_cast(int, f)));
}
__device__ __forceinline__ int sreadi(int v) {
    return __builtin_amdgcn_readfirstlane(v);
}

// ---------------------------------------------------------------------------
// Fused prep: blocks [0,1024) transpose x -> channels-last bf16 xt;
//             blocks [1024,3328) pack weight -> 32x32x16 A-fragment order:
//   wq[ ((m*144 + ks)*64 + lane)*8 + j ] = W[o = m*32 + (lane&31)]
//                                           [k = ks*16 + (lane>>5)*8 + j]
//   (k decomposes as tap = k>>8, cin = k&255)
// ---------------------------------------------------------------------------
__global__ __launch_bounds__(256) void prep_k(const float* __restrict__ x,
                                              const float* __restrict__ w,
                                              bf16* __restrict__ xt,
                                              bf16* __restrict__ wq) {
    int bid = blockIdx.x;
    int tid = threadIdx.x;
    if (bid < 1024) {
        __shared__ bf16 tile[64][72];        // px-major; rows 144 B
        int pt = bid & 63, ct = (bid >> 6) & 3, b = bid >> 8;
        int lane = tid & 63, row = tid >> 6;
        const float* src = x + ((size_t)(b * 256 + ct * 64)) * 4096 + pt * 64;
        #pragma unroll
        for (int cc = row; cc < 64; cc += 4)
            tile[lane][cc] = (bf16)src[(size_t)cc * 4096 + lane];
        __syncthreads();
        bf16* dst = xt + ((size_t)(b * 4096 + pt * 64)) * 256 + ct * 64;
        int p = tid >> 3, j = tid & 7;
        #pragma unroll
        for (int pp = p; pp < 64; pp += 32)
            *reinterpret_cast<bf16x8*>(dst + (size_t)pp * 256 + j * 8) =
                *reinterpret_cast<const bf16x8*>(&tile[pp][j * 8]);
    } else {
        int idx  = (bid - 1024) * 256 + tid;   // < 589824
        int j    = idx & 7;
        int lane = (idx >> 3) & 63;
        int rest = idx >> 9;                   // m*144 + ks, < 1152
        int ks   = rest % KSTEPS;
        int m    = rest / KSTEPS;
        int o    = m * 32 + (lane & 31);
        int k    = ks * 16 + (lane >> 5) * 8 + j;
        int tap  = k >> 8;
        int cc   = k & 255;
        wq[idx] = (bf16)w[(size_t)o * KDIM + cc * KK + tap];
    }
}

// ---------------------------------------------------------------------------
// Fused sampling -> LDS -> 32x32x16 MFMA GEMM with K-split waves.
// WG = 1024 thr (16 waves), PXW=32, grid 512 -> 2 WG/CU = 32 waves/CU.
// Wave (mt = wavei&7, kh = wavei>>3): output chans [mt*32, mt*32+32) x all
// 32 px, K-half kh (within-tap cin 0..127 / 128..255). acc = one f32x16.
// Per MFMA (32 KFLOP): ONE global A b128 + ONE LDS B b128 -> LDS b128
// reads/CU halve vs the 16x16x32 version (4608 -> 2304) and the MFMA
// instruction count halves at identical FLOPs. K-halves are summed once
// through LDS in the epilogue.
// LDS swizzle: full 5-bit XOR (16B slot ^ (row&31)) -> sampling write is a
// row permutation (conflict-free) and GEMM read hits 32 distinct slots per
// half-wave (conflict-free), vs 4.7M conflict cycles for the old 3-bit XOR.
// Double-buffered S, ONE barrier per tap (t+2's writes to S[t&1] are
// ordered behind barrier t+1). 4 A-frags prefetched before the barrier so
// their L2 latency drains with the barrier's vmcnt(0) instead of stalling
// the first MFMAs. XCD band swizzle + tap rotation kept.
// ---------------------------------------------------------------------------
__global__ __launch_bounds__(1024, 8) void deform_gemm_k(
    const bf16*  __restrict__ xt,
    const float* __restrict__ off,
    const bf16*  __restrict__ wq,
    const float* __restrict__ bias,
    float*       __restrict__ out) {

    __shared__ bf16 S[2][PXW * 256];   // 2 x 16 KB, swizzled 16B granules

    int tid   = threadIdx.x;
    int wavei = sreadi(tid >> 6);   // 0..15
    int lane  = tid & 63;
    int l32   = lane & 31;
    int half  = lane >> 5;
    int mt    = wavei & 7;          // mtile (32 output channels)
    int kh    = wavei >> 3;         // K-half within each tap

    int bid   = blockIdx.x;                      // 0..511
    int pb    = ((bid & 7) << 6) | (bid >> 3);   // XCD-band pixel-block
    int pix0  = pb * PXW;
    int b     = pix0 >> 12;                      // WG-uniform batch
    int pimgb = pix0 & 4095;
    int obase = b * 73728;                       // scalar base into off[]
    unsigned base = (unsigned)b * 1048576u + (unsigned)(lane * 4); // into xt[]
    int rot   = ((bid >> 3) & 1) * 4;            // co-resident WG desync

    f32x16 acc;
    #pragma unroll
    for (int r = 0; r < 16; ++r) acc[r] = 0.f;

    for (int t = 0; t < KK; ++t) {
        int tap = t + rot; if (tap >= KK) tap -= KK;
        int ty = tap / 3 - 1;
        int tx = tap % 3 - 1;
        bf16* Sw = &S[t & 1][0];

        // ---- sampling: wave fills rows n = wavei*2, wavei*2+1 ----
        #pragma unroll
        for (int i = 0; i < 2; ++i) {
            int n    = wavei * 2 + i;
            int pimg = pimgb + n;                          // scalar
            float oy = off[obase + pimg + (2 * tap) * 4096];      // s_load
            float ox = off[obase + pimg + (2 * tap + 1) * 4096];  // s_load
            float py = (float)((pimg >> 6) + ty) + oy;
            float px = (float)((pimg & 63) + tx) + ox;
            float fy = floorf(py), fx = floorf(px);
            int   y0 = (int)fy,    x0 = (int)fx;
            float wy1 = py - fy, wx1 = px - fx;
            float wy0 = 1.f - wy1, wx0 = 1.f - wx1;
            wy0 = ((unsigned)y0       < 64u) ? wy0 : 0.f;
            wy1 = ((unsigned)(y0 + 1) < 64u) ? wy1 : 0.f;
            wx0 = ((unsigned)x0       < 64u) ? wx0 : 0.f;
            wx1 = ((unsigned)(x0 + 1) < 64u) ? wx1 : 0.f;
            int yc0 = min(max(y0, 0), 63), yc1 = min(max(y0 + 1, 0), 63);
            int xc0 = min(max(x0, 0), 63), xc1 = min(max(x0 + 1, 0), 63);
            int u0 = sreadi((yc0 * 64 + xc0) * 256);
            int u1 = sreadi((yc0 * 64 + xc1) * 256);
            int u2 = sreadi((yc1 * 64 + xc0) * 256);
            int u3 = sreadi((yc1 * 64 + xc1) * 256);
            float w0 = sread(wy0 * wx0), w1 = sread(wy0 * wx1);
            float w2 = sread(wy1 * wx0), w3 = sread(wy1 * wx1);
            bf16x4 v0 = *reinterpret_cast<const bf16x4*>(xt + base + (unsigned)u0);
            bf16x4 v1 = *reinterpret_cast<const bf16x4*>(xt + base + (unsigned)u1);
            bf16x4 v2 = *reinterpret_cast<const bf16x4*>(xt + base + (unsigned)u2);
            bf16x4 v3 = *reinterpret_cast<const bf16x4*>(xt + base + (unsigned)u3);
            float a0 = w0 * (float)v0[0] + w1 * (float)v1[0]
                     + w2 * (float)v2[0] + w3 * (float)v3[0];
            float a1 = w0 * (float)v0[1] + w1 * (float)v1[1]
                     + w2 * (float)v2[1] + w3 * (float)v3[1];
            float a2 = w0 * (float)v0[2] + w1 * (float)v1[2]
                     + w2 * (float)v2[2] + w3 * (float)v3[2];
            float a3 = w0 * (float)v0[3] + w1 * (float)v1[3]
                     + w2 * (float)v2[3] + w3 * (float)v3[3];
            bf16x4 sv;
            sv[0] = (bf16)a0; sv[1] = (bf16)a1;
            sv[2] = (bf16)a2; sv[3] = (bf16)a3;
            // ch = lane*4 -> 16B slot (lane>>1), half (lane&1); 5-bit XOR
            int gs = (lane >> 1) ^ (n & 31);
            *reinterpret_cast<bf16x4*>(Sw + n * 256 + gs * 8 + (lane & 1) * 4) = sv;
        }

        // A pointer for this tap; prefetch 4 frags before the barrier so
        // the barrier's vmcnt(0) drain covers their latency.
        const bf16* ap0 = wq +
            ((size_t)(((mt * KSTEPS) + tap * 16 + kh * 8) * 64 + lane)) * 8;
        bf16x8 a0 = *reinterpret_cast<const bf16x8*>(ap0);
        bf16x8 a1 = *reinterpret_cast<const bf16x8*>(ap0 + 512);
        bf16x8 a2 = *reinterpret_cast<const bf16x8*>(ap0 + 1024);
        bf16x8 a3 = *reinterpret_cast<const bf16x8*>(ap0 + 1536);

        __syncthreads();

        // ---- GEMM over this wave's K-half (128 of the tap's 256) ----
        const bf16* Sr = Sw;
        #pragma unroll
        for (int kk2 = 0; kk2 < 8; ++kk2) {
            bf16x8 a;
            if      (kk2 == 0) a = a0;
            else if (kk2 == 1) a = a1;
            else if (kk2 == 2) a = a2;
            else if (kk2 == 3) a = a3;
            else a = *reinterpret_cast<const bf16x8*>(ap0 + (size_t)kk2 * 512);
            int s  = kh * 8 + kk2;              // K-step within tap, 0..15
            int g  = s * 2 + half;              // 16B slot (cin base >> 3)
            int gs = g ^ l32;                   // row = l32 (pixel/col)
            bf16x8 bf = *reinterpret_cast<const bf16x8*>(Sr + l32 * 256 + gs * 8);
            acc = __builtin_amdgcn_mfma_f32_32x32x16_bf16(a, bf, acc, 0, 0, 0);
        }
        // no second barrier: next tap writes the OTHER buffer; re-write of
        // this buffer (t+2) is ordered behind barrier t+1.
    }

    // ---- epilogue: sum the two K-halves through LDS, then store ----
    __syncthreads();                 // all GEMM reads of S done
    float* Sf = reinterpret_cast<float*>(&S[0][0]);   // 8192 f32 = 32 KB
    if (wavei >= 8) {
        int wb = (wavei - 8) * 64 + lane;
        #pragma unroll
        for (int r = 0; r < 16; ++r)
            Sf[r * 512 + wb] = acc[r];   // lane-major: conflict-free b32
    }
    __syncthreads();
    if (wavei < 8) {
        // C/D layout (32x32x16): col = lane&31, row = (r&3)+8*(r>>2)+4*half
        int wb   = wavei * 64 + lane;
        int m    = mt * 32;              // mt == wavei here (kh == 0)
        int pimg = pimgb + l32;
        float* op = out + ((size_t)(b * 256 + m)) * 4096 + pimg;
        #pragma unroll
        for (int r = 0; r < 16; ++r) {
            int row = (r & 3) + 8 * (r >> 2) + half * 4;
            float v = acc[r] + Sf[r * 512 + wb] + bias[m + row];
            op[(size_t)row * 4096] = v;
        }
    }
}

// ---------------------------------------------------------------------------
extern "C" void kernel_launch(void* const* d_in, const int* in_sizes, int n_in,
                              void* d_out, int out_size, void* d_ws, size_t ws_size,
                              hipStream_t stream) {
    const float* x    = (const float*)d_in[0];   // [4,256,64,64]
    const float* off  = (const float*)d_in[1];   // [4,18,64,64]
    const float* w    = (const float*)d_in[2];   // [256,256,3,3]
    const float* bias = (const float*)d_in[3];   // [256]
    float* out = (float*)d_out;                  // [4,256,64,64]

    bf16* wq = (bf16*)d_ws;                               // 1,179,648 B
    bf16* xt = (bf16*)((char*)d_ws + (size_t)589824 * 2); // 8,388,608 B

    prep_k<<<3328, 256, 0, stream>>>(x, w, xt, wq);
    deform_gemm_k<<<512, 1024, 0, stream>>>(xt, off, wq, bias, out);
}